// Round 22
// baseline (296.926 us; speedup 1.0000x reference)
//
#include <hip/hip_runtime.h>

// DenseAttention — reassociated (6.44 GF vs 155 GF direct), bf16 MFMA.
// Round 25: SPLIT-PROBE on the r24 best (124.7us). r24 post-mortem: swizzle
// win matched prediction (conflict lever validated, now mostly spent: remaining
// stagers are at/near their bank floors). Chain = 43.3 fill + 81.4 kernels,
// but the per-kernel split is unknown and my estimates failed twice (r21/r22).
// PROBE: full chain once + back half (gred->2a->2b->k_3) repeated 4 extra
// times. All are deterministic pure functions of fixed inputs -> bit-identical
// rewrites; absmax must stay exactly 0.001953125.
// W2 = (dur - 124.7)/4 = warm {gred+2a+2b+k_3 + gaps}.
//   W2 < 20 : k_1 dominates -> attack gram staging next.
//   W2 >= 28: back half dominates -> retile/fuse 2a/k_3 next.
// Chain (r24-verbatim):
//   K1:   gram 128x128 swizzled (256 blk) || prep (64 blk)  grid 320
//   gred: Gsbf[bq] = bf16(sum_s Gp[s][bq])   grid 512
//   2a:   Tt[ba][g][qf] = combt_g . Gsbf_f   grid(16,32)=512
//   2b:   Wtbf[ba][g][e] = Tt_g . qwbf_e     grid(16,8)=128, K=1024 in-block
//   out:  out[t][ag] = bf16(x)_t . Wtbf_g    grid(32,8)=256, 64x256 tiles
// ws (26 MB): Gp 16 | Tt 4 | qwbf 2 | combt 2 | Wtbf 1 | Gsbf 1.

typedef unsigned short u16;
using short8  = __attribute__((ext_vector_type(8))) short;
using floatx4 = __attribute__((ext_vector_type(4))) float;

__device__ inline u16 f2bf(float f) {               // RNE f32->bf16
    unsigned u = __float_as_uint(f);
    unsigned r = u + 0x7fffu + ((u >> 16) & 1u);
    return (u16)(r >> 16);
}

// ---------------- stagers -----------------------------------------------------
// bf16 row-major [64 m][64 k] -> fragment-major LDS. 2x(16B load + b128 write).
__device__ inline void stage64_bf(const u16* __restrict__ src, long ld,
                                  u16* __restrict__ dst, int tid) {
#pragma unroll
    for (int it = 0; it < 2; ++it) {
        const int flat = (it * 256 + tid) * 8;
        const int kl = flat & 63, rl = flat >> 6;
        const short8 v = *(const short8*)&src[(long)rl * ld + kl];
        const int chunk = ((kl >> 5) * 4 + (rl >> 4)) * 64 + ((kl >> 3) & 3) * 16 + (rl & 15);
        *(short8*)&dst[chunk * 8] = v;
    }
}

// f32 row-major [64 m][64 k] -> fragment-major LDS (f2bf in-stager).
__device__ inline void stage64_f32(const float* __restrict__ src, long ld,
                                   u16* __restrict__ dst, int tid) {
#pragma unroll
    for (int it = 0; it < 4; ++it) {
        const int flat = (it * 256 + tid) * 4;
        const int kl = flat & 63, rl = flat >> 6;
        const float4 f = *(const float4*)&src[(long)rl * ld + kl];
        ushort4 v;
        v.x = f2bf(f.x); v.y = f2bf(f.y); v.z = f2bf(f.z); v.w = f2bf(f.w);
        const int chunk = ((kl >> 5) * 4 + (rl >> 4)) * 64 + ((kl >> 3) & 3) * 16 + (rl & 15);
        *(ushort4*)&dst[chunk * 8 + (kl & 7)] = v;
    }
}

// K-major f32 [64 k][128 m] -> 128-row fragment-major block, XOR-SWIZZLED
// (r24-verified): chunk = row*64 + (lane ^ (row&7)), j = k&7.
__device__ inline void stage_km128_sw(const float* __restrict__ src, long ld,
                                      u16* __restrict__ dst, int tid) {
#pragma unroll
    for (int it = 0; it < 8; ++it) {
        const int flat = (it * 256 + tid) * 4;
        const int m = flat & 127, k = flat >> 7;
        const float4 f = *(const float4*)&src[(long)k * ld + m];
        const int row = (k >> 5) * 8 + (m >> 4);
        const int lb  = ((k & 31) >> 3) * 16 + (m & 15);
        const int sw  = row & 7;
        const int b16 = row * 64;
        const int j = k & 7;
        dst[(b16 + ((lb + 0) ^ sw)) * 8 + j] = f2bf(f.x);
        dst[(b16 + ((lb + 1) ^ sw)) * 8 + j] = f2bf(f.y);
        dst[(b16 + ((lb + 2) ^ sw)) * 8 + j] = f2bf(f.z);
        dst[(b16 + ((lb + 3) ^ sw)) * 8 + j] = f2bf(f.w);
    }
}

// ---------------- 64x64-tile GEMM body, KR rounds of K=256 -------------------
// AM/BM: 0 = bf16 row-major, 1 = f32 row-major.
template <int AM, int BM, typename TC, int KR>
__device__ inline void gemm_tile(const void* __restrict__ Av, long lda,
                                 const void* __restrict__ Bv, long ldb,
                                 TC* __restrict__ C, long ldc,
                                 int m0, int n0) {
    __shared__ u16 As[16384];   // 32 KB: 4 x 64-k fragment blocks
    __shared__ u16 Bs[16384];
    const int tid = threadIdx.x, lane = tid & 63, w = tid >> 6;
    const int IA = (w & 1) * 2, JB = (w >> 1) * 2;
    floatx4 acc[2][2] = {};

#pragma unroll
    for (int r = 0; r < KR; ++r) {
        if (r) __syncthreads();
#pragma unroll
        for (int kb = 0; kb < 4; ++kb) {
            if (AM == 0) stage64_bf ((const u16*)Av   + r * 256 + kb * 64, lda, As + kb * 4096, tid);
            else         stage64_f32((const float*)Av + r * 256 + kb * 64, lda, As + kb * 4096, tid);
            if (BM == 0) stage64_bf ((const u16*)Bv   + r * 256 + kb * 64, ldb, Bs + kb * 4096, tid);
            else         stage64_f32((const float*)Bv + r * 256 + kb * 64, ldb, Bs + kb * 4096, tid);
        }
        __syncthreads();

#pragma unroll
        for (int kb = 0; kb < 4; ++kb)
#pragma unroll
            for (int s = 0; s < 2; ++s) {
                short8 af[2], bfr[2];
#pragma unroll
                for (int i = 0; i < 2; ++i)
                    af[i] = *(const short8*)&As[kb * 4096 + ((s * 4 + IA + i) * 64 + lane) * 8];
#pragma unroll
                for (int j = 0; j < 2; ++j)
                    bfr[j] = *(const short8*)&Bs[kb * 4096 + ((s * 4 + JB + j) * 64 + lane) * 8];
#pragma unroll
                for (int i = 0; i < 2; ++i)
#pragma unroll
                    for (int j = 0; j < 2; ++j)
                        acc[i][j] = __builtin_amdgcn_mfma_f32_16x16x32_bf16(af[i], bfr[j], acc[i][j], 0, 0, 0);
            }
    }

    const int rb = (lane >> 4) * 4, col = lane & 15;
#pragma unroll
    for (int i = 0; i < 2; ++i)
#pragma unroll
        for (int j = 0; j < 2; ++j)
#pragma unroll
            for (int r = 0; r < 4; ++r) {
                const int gm = m0 + (IA + i) * 16 + rb + r;
                const int gn = n0 + (JB + j) * 16 + col;
                TC* p = &C[(long)gm * ldc + gn];
                if (sizeof(TC) == 2) *(u16*)p = f2bf(acc[i][j][r]);
                else                 *(float*)p = acc[i][j][r];
            }
}

// ---------------- K1: gram 128x128 (256 blk, swizzled) || prep (64 blk) ------
__global__ __launch_bounds__(256) void k_1(const float* __restrict__ x,
                                           const float* __restrict__ qw,
                                           const float* __restrict__ comb,
                                           float* __restrict__ Gp,
                                           u16* __restrict__ qwbf,
                                           u16* __restrict__ combt) {
    __shared__ u16 As[16384];   // 32 KB: 2 x (128m x 64k) fragment blocks
    __shared__ u16 Bs[16384];
    const int bid = blockIdx.x, tid = threadIdx.x;

    if (bid < 256) {            // ---- gram ----
        const int tl = bid & 3, bq = (bid >> 2) & 7, split = bid >> 5;
        const int tm = tl >> 1, tn = tl & 1;
        const int b = bq >> 2, q = bq & 3;
        const int lane = tid & 63, w = tid >> 6;
        const int IA2 = (w & 1), JB2 = (w >> 1);     // wave's 64x64 quadrant

        const float* base = x + (long)b * 2097152 + (long)split * 262144 + q * 256;
        const float* A = base + tm * 128;    // [k=u][m=f], ld 1024
        const float* B = base + tn * 128;
        floatx4 acc[4][4] = {};

#pragma unroll
        for (int burst = 0; burst < 2; ++burst) {
            if (burst) __syncthreads();
#pragma unroll
            for (int kb = 0; kb < 2; ++kb) {
                const long kk = burst * 128 + kb * 64;
                stage_km128_sw(A + kk * 1024, 1024, As + kb * 8192, tid);
                stage_km128_sw(B + kk * 1024, 1024, Bs + kb * 8192, tid);
            }
            __syncthreads();
#pragma unroll
            for (int kb = 0; kb < 2; ++kb)
#pragma unroll
                for (int s = 0; s < 2; ++s) {
                    short8 af[4], bfr[4];
#pragma unroll
                    for (int i = 0; i < 4; ++i) {
                        const int rA = s * 8 + IA2 * 4 + i;
                        af[i] = *(const short8*)&As[kb * 8192 + (rA * 64 + (lane ^ (rA & 7))) * 8];
                    }
#pragma unroll
                    for (int j = 0; j < 4; ++j) {
                        const int rB = s * 8 + JB2 * 4 + j;
                        bfr[j] = *(const short8*)&Bs[kb * 8192 + (rB * 64 + (lane ^ (rB & 7))) * 8];
                    }
#pragma unroll
                    for (int i = 0; i < 4; ++i)
#pragma unroll
                        for (int j = 0; j < 4; ++j)
                            acc[i][j] = __builtin_amdgcn_mfma_f32_16x16x32_bf16(af[i], bfr[j], acc[i][j], 0, 0, 0);
                }
        }

        float* C = Gp + (long)(split * 8 + bq) * 65536;
        const int rb = (lane >> 4) * 4, col = lane & 15;
#pragma unroll
        for (int i = 0; i < 4; ++i)
#pragma unroll
            for (int j = 0; j < 4; ++j)
#pragma unroll
                for (int r = 0; r < 4; ++r) {
                    const int gm = tm * 128 + IA2 * 64 + i * 16 + rb + r;
                    const int gn = tn * 128 + JB2 * 64 + j * 16 + col;
                    C[(long)gm * 256 + gn] = acc[i][j][r];
                }
    } else {                    // ---- prep: 768 units over 64 blocks ----
        for (int u = bid - 256; u < 768; u += 64) {
            if (u < 512) {                  // qwbf: 512 units x 2048 elems
                const long i = ((long)u * 256 + tid) * 8;
                const float4 a = *(const float4*)&qw[i];
                const float4 b = *(const float4*)&qw[i + 4];
                ushort4 lo, hi;
                lo.x = f2bf(a.x); lo.y = f2bf(a.y); lo.z = f2bf(a.z); lo.w = f2bf(a.w);
                hi.x = f2bf(b.x); hi.y = f2bf(b.y); hi.z = f2bf(b.z); hi.w = f2bf(b.w);
                *(ushort4*)&qwbf[i]     = lo;
                *(ushort4*)&qwbf[i + 4] = hi;
            } else {                        // combt[a][g][qh] = comb[a][qh][g]
                u16 (*T)[66] = (u16(*)[66])As;      // scratch in As
                const int t = u - 512;      // 256 units: 4 a x 16 qh x 4 g
                const int a = t >> 6;
                const int qh0 = ((t >> 2) & 15) * 64, g0 = (t & 3) * 64;
                const float* src = comb + (long)a * 262144;   // [1024 qh][256 g]
                u16* dst = combt + (long)a * 262144;          // [256 g][1024 qh]
                __syncthreads();            // protect T reuse across units
#pragma unroll
                for (int it = 0; it < 4; ++it) {
                    const int flat = (it * 256 + tid) * 4;
                    const int r = flat >> 6, c = flat & 63;
                    const float4 f = *(const float4*)&src[(long)(qh0 + r) * 256 + g0 + c];
                    T[r][c]     = f2bf(f.x); T[r][c + 1] = f2bf(f.y);
                    T[r][c + 2] = f2bf(f.z); T[r][c + 3] = f2bf(f.w);
                }
                __syncthreads();
#pragma unroll
                for (int it = 0; it < 4; ++it) {
                    const int flat = (it * 256 + tid) * 4;
                    const int r = flat >> 6, c = flat & 63;
                    ushort4 v;
                    v.x = T[c][r]; v.y = T[c + 1][r]; v.z = T[c + 2][r]; v.w = T[c + 3][r];
                    *(ushort4*)&dst[(long)(g0 + r) * 1024 + qh0 + c] = v;
                }
            }
        }
    }
}

// gred: Gsbf[bq][f][h] = bf16(sum_{s=0..7} Gp[s][bq][f][h]). 524288 elems.
__global__ __launch_bounds__(256) void k_gred(const float* __restrict__ Gp,
                                              u16* __restrict__ Gs) {
    const long i = ((long)blockIdx.x * 256 + threadIdx.x) * 4;
    float4 acc = *(const float4*)&Gp[i];
#pragma unroll
    for (int s = 1; s < 8; ++s) {
        const float4 f = *(const float4*)&Gp[(long)s * 524288 + i];
        acc.x += f.x; acc.y += f.y; acc.z += f.z; acc.w += f.w;
    }
    ushort4 v;
    v.x = f2bf(acc.x); v.y = f2bf(acc.y); v.z = f2bf(acc.z); v.w = f2bf(acc.w);
    *(ushort4*)&Gs[i] = v;
}

// 2a: Tt[ba][g][q*256+f] = sum_h combt[a][g][q*256+h] * Gsbf[bq][f][h]
__global__ __launch_bounds__(256) void k_2a(const u16* __restrict__ combt,
                                            const u16* __restrict__ Gs,
                                            u16* __restrict__ Tt) {
    const int tile = blockIdx.x, i = blockIdx.y;     // i = ba*4+q
    const int tm = tile >> 2, tn = tile & 3;
    const int q = i & 3, ba = i >> 2, b = ba >> 2, a = ba & 3;
    gemm_tile<0, 0, u16, 1>(
        combt + (long)a * 262144 + (long)tm * 65536 + q * 256, 1024,
        Gs + (long)(b * 4 + q) * 65536 + (long)tn * 16384, 256,
        Tt + (long)ba * 262144, 1024,
        tm * 64, q * 256 + tn * 64);
}

// 2b: Wtbf[ba][g][e] = sum_k Tt[ba][g][k] * qwbf[a][e][k], K=1024 in-block.
__global__ __launch_bounds__(256) void k_2b(const u16* __restrict__ Tt,
                                            const u16* __restrict__ qwbf,
                                            u16* __restrict__ Wt) {
    const int tile = blockIdx.x, ba = blockIdx.y;
    const int tm = tile >> 2, tn = tile & 3;
    const int a = ba & 3;
    gemm_tile<0, 0, u16, 4>(
        Tt + (long)ba * 262144 + (long)tm * 65536, 1024,
        qwbf + (long)a * 262144 + (long)tn * 65536, 1024,
        Wt + (long)ba * 65536, 256,
        tm * 64, tn * 64);
}

// out: out[b][t][a*256+g] = sum_e bf16(x[b][t][a*256+e]) * Wtbf[ba][g][e]
// 64x256 output tile per block (r22/r24 body).
__global__ __launch_bounds__(256) void k_3(const float* __restrict__ x,
                                           const u16* __restrict__ Wt,
                                           float* __restrict__ out) {
    __shared__ u16 As[4096];    //  8 KB: 64t x 64e fragment block
    __shared__ u16 Bs[16384];   // 32 KB: 4 g-blocks x (64g x 64e)
    const int tm = blockIdx.x, ba = blockIdx.y;      // tm 0..31, ba 0..7
    const int b = ba >> 2, a = ba & 3;
    const int tid = threadIdx.x, lane = tid & 63, w = tid >> 6;
    const float* A = x + (long)b * 2097152 + (long)tm * 65536 + a * 256;  // ld 1024
    const u16*   B = Wt + (long)ba * 65536;                               // [256 g][256 e]
    floatx4 acc[4][4] = {};

#pragma unroll
    for (int kb = 0; kb < 4; ++kb) {
        if (kb) __syncthreads();
        stage64_f32(A + kb * 64, 1024, As, tid);
#pragma unroll
        for (int jb = 0; jb < 4; ++jb)
            stage64_bf(B + (long)jb * 16384 + kb * 64, 256, Bs + jb * 4096, tid);
        __syncthreads();
#pragma unroll
        for (int s = 0; s < 2; ++s) {
            short8 af[4], bfr[4];
#pragma unroll
            for (int i = 0; i < 4; ++i)
                af[i] = *(const short8*)&As[((s * 4 + i) * 64 + lane) * 8];
#pragma unroll
            for (int j = 0; j < 4; ++j)
                bfr[j] = *(const short8*)&Bs[w * 4096 + ((s * 4 + j) * 64 + lane) * 8];
#pragma unroll
            for (int i = 0; i < 4; ++i)
#pragma unroll
                for (int j = 0; j < 4; ++j)
                    acc[i][j] = __builtin_amdgcn_mfma_f32_16x16x32_bf16(af[i], bfr[j], acc[i][j], 0, 0, 0);
        }
    }

    float* C = out + (long)b * 2097152 + a * 256;
    const int rb = (lane >> 4) * 4, col = lane & 15;
#pragma unroll
    for (int i = 0; i < 4; ++i)
#pragma unroll
        for (int j = 0; j < 4; ++j)
#pragma unroll
            for (int r = 0; r < 4; ++r) {
                const int gm = tm * 64 + i * 16 + rb + r;          // t row
                const int gn = w * 64 + j * 16 + col;              // g col (0..255)
                C[(long)gm * 1024 + gn] = acc[i][j][r];
            }
}

extern "C" void kernel_launch(void* const* d_in, const int* in_sizes, int n_in,
                              void* d_out, int out_size, void* d_ws, size_t ws_size,
                              hipStream_t stream) {
    const float* x    = (const float*)d_in[0];   // [2,2048,1024]
    const float* qw   = (const float*)d_in[1];   // [4,256,1024]
    const float* comb = (const float*)d_in[2];   // [4,1024,256]
    float* out = (float*)d_out;

    char* ws = (char*)d_ws;
    float* Gp   = (float*)(ws);                  // 16 MB [8 split][8 bq][256x256]
    u16*   Tt   = (u16*)  (ws + (16u << 20));    //  4 MB [8][256][1024] bf16
    u16*   qwbf = (u16*)  (ws + (20u << 20));    //  2 MB [4][256][1024] bf16
    u16*   combt= (u16*)  (ws + (22u << 20));    //  2 MB [4][256][1024] bf16 (comb^T)
    u16*   Wtbf = (u16*)  (ws + (24u << 20));    //  1 MB [8][256][256] bf16
    u16*   Gsbf = (u16*)  (ws + (25u << 20));    //  1 MB [8 bq][256][256] bf16

    k_1 <<<dim3(320), 256, 0, stream>>>(x, qw, comb, Gp, qwbf, combt);
    // PROBE: back half x5 (all pure functions of fixed inputs ->
    // bit-identical rewrites). W2 = (dur - 124.7)/4.
    for (int rep = 0; rep < 5; ++rep) {
        k_gred<<<dim3(512),    256, 0, stream>>>(Gp, Gsbf);
        k_2a  <<<dim3(16, 32), 256, 0, stream>>>(combt, Gsbf, Tt);
        k_2b  <<<dim3(16, 8),  256, 0, stream>>>(Tt, qwbf, Wtbf);
        k_3   <<<dim3(32, 8),  256, 0, stream>>>(x, Wtbf, out);
    }
}

// Round 23
// 124.263 us; speedup vs baseline: 2.3895x; 2.3895x over previous
//
#include <hip/hip_runtime.h>

// DenseAttention — reassociated (6.44 GF vs 155 GF direct), bf16 MFMA.
// Round 26: r24 best (124.7us) + gram stager vectorized.
// r25 probe: warm back half = 43.1us (4 kernels, ~5-8us/dispatch overhead +
// ~20us work); warm k_1 ~ 15-18us = biggest single kernel. r24 showed gram's
// cost is the staging WRITE stream: 32 scalar ds_write_b16/thread/call at
// ~4-way. Fix: thread owns (m, k-group-of-8): 8 coalesced global_load_dword
// (stride ld, lanes consecutive m) + 8 f2bf + ONE ds_write_b128 at the SAME
// swizzled chunk as r24 -> LDS image BIT-IDENTICAL, write instrs 8x fewer.
// Reads (XOR'd fragment loads) unchanged from r24.
//   K1:   gram 128x128 swizzled (256 blk) || prep (64 blk)  grid 320
//   gred: Gsbf[bq] = bf16(sum_s Gp[s][bq])   grid 512
//   2a:   Tt[ba][g][qf] = combt_g . Gsbf_f   grid(16,32)=512
//   2b:   Wtbf[ba][g][e] = Tt_g . qwbf_e     grid(16,8)=128, K=1024 in-block
//   out:  out[t][ag] = bf16(x)_t . Wtbf_g    grid(32,8)=256, 64x256 tiles
// ws (26 MB): Gp 16 | Tt 4 | qwbf 2 | combt 2 | Wtbf 1 | Gsbf 1.

typedef unsigned short u16;
using short8  = __attribute__((ext_vector_type(8))) short;
using floatx4 = __attribute__((ext_vector_type(4))) float;

__device__ inline u16 f2bf(float f) {               // RNE f32->bf16
    unsigned u = __float_as_uint(f);
    unsigned r = u + 0x7fffu + ((u >> 16) & 1u);
    return (u16)(r >> 16);
}

// ---------------- stagers -----------------------------------------------------
// bf16 row-major [64 m][64 k] -> fragment-major LDS. 2x(16B load + b128 write).
__device__ inline void stage64_bf(const u16* __restrict__ src, long ld,
                                  u16* __restrict__ dst, int tid) {
#pragma unroll
    for (int it = 0; it < 2; ++it) {
        const int flat = (it * 256 + tid) * 8;
        const int kl = flat & 63, rl = flat >> 6;
        const short8 v = *(const short8*)&src[(long)rl * ld + kl];
        const int chunk = ((kl >> 5) * 4 + (rl >> 4)) * 64 + ((kl >> 3) & 3) * 16 + (rl & 15);
        *(short8*)&dst[chunk * 8] = v;
    }
}

// f32 row-major [64 m][64 k] -> fragment-major LDS (f2bf in-stager).
__device__ inline void stage64_f32(const float* __restrict__ src, long ld,
                                   u16* __restrict__ dst, int tid) {
#pragma unroll
    for (int it = 0; it < 4; ++it) {
        const int flat = (it * 256 + tid) * 4;
        const int kl = flat & 63, rl = flat >> 6;
        const float4 f = *(const float4*)&src[(long)rl * ld + kl];
        ushort4 v;
        v.x = f2bf(f.x); v.y = f2bf(f.y); v.z = f2bf(f.z); v.w = f2bf(f.w);
        const int chunk = ((kl >> 5) * 4 + (rl >> 4)) * 64 + ((kl >> 3) & 3) * 16 + (rl & 15);
        *(ushort4*)&dst[chunk * 8 + (kl & 7)] = v;
    }
}

// K-major f32 [64 k][128 m] -> 128-row fragment-major block, XOR-SWIZZLED,
// VECTORIZED writes (r26): thread owns (m, kg): 8 coalesced column loads
// (lane-consecutive m -> 256B/instr) + one ds_write_b128 at
// chunk = row*64 + (lanepart ^ (row&7)), lanepart=(kg&3)*16+(m&15),
// row=(kg>>2)*8+(m>>4). Same LDS image as r24's scalar scatter (bit-exact).
__device__ inline void stage_km128_v(const float* __restrict__ src, long ld,
                                     u16* __restrict__ dst, int tid) {
#pragma unroll
    for (int it = 0; it < 4; ++it) {
        const int u = it * 256 + tid;          // 0..1023
        const int m = u & 127, kg = u >> 7;    // kg 0..7 (k = kg*8 + j)
        const int row = (kg >> 2) * 8 + (m >> 4);
        const int lanepart = (kg & 3) * 16 + (m & 15);
        const int chunk = row * 64 + (lanepart ^ (row & 7));
        const float* col = src + (long)(kg * 8) * ld + m;
        short8 v;
#pragma unroll
        for (int j = 0; j < 8; ++j)
            v[j] = (short)f2bf(col[(long)j * ld]);
        *(short8*)&dst[chunk * 8] = v;
    }
}

// ---------------- 64x64-tile GEMM body, KR rounds of K=256 -------------------
// AM/BM: 0 = bf16 row-major, 1 = f32 row-major.
template <int AM, int BM, typename TC, int KR>
__device__ inline void gemm_tile(const void* __restrict__ Av, long lda,
                                 const void* __restrict__ Bv, long ldb,
                                 TC* __restrict__ C, long ldc,
                                 int m0, int n0) {
    __shared__ u16 As[16384];   // 32 KB: 4 x 64-k fragment blocks
    __shared__ u16 Bs[16384];
    const int tid = threadIdx.x, lane = tid & 63, w = tid >> 6;
    const int IA = (w & 1) * 2, JB = (w >> 1) * 2;
    floatx4 acc[2][2] = {};

#pragma unroll
    for (int r = 0; r < KR; ++r) {
        if (r) __syncthreads();
#pragma unroll
        for (int kb = 0; kb < 4; ++kb) {
            if (AM == 0) stage64_bf ((const u16*)Av   + r * 256 + kb * 64, lda, As + kb * 4096, tid);
            else         stage64_f32((const float*)Av + r * 256 + kb * 64, lda, As + kb * 4096, tid);
            if (BM == 0) stage64_bf ((const u16*)Bv   + r * 256 + kb * 64, ldb, Bs + kb * 4096, tid);
            else         stage64_f32((const float*)Bv + r * 256 + kb * 64, ldb, Bs + kb * 4096, tid);
        }
        __syncthreads();

#pragma unroll
        for (int kb = 0; kb < 4; ++kb)
#pragma unroll
            for (int s = 0; s < 2; ++s) {
                short8 af[2], bfr[2];
#pragma unroll
                for (int i = 0; i < 2; ++i)
                    af[i] = *(const short8*)&As[kb * 4096 + ((s * 4 + IA + i) * 64 + lane) * 8];
#pragma unroll
                for (int j = 0; j < 2; ++j)
                    bfr[j] = *(const short8*)&Bs[kb * 4096 + ((s * 4 + JB + j) * 64 + lane) * 8];
#pragma unroll
                for (int i = 0; i < 2; ++i)
#pragma unroll
                    for (int j = 0; j < 2; ++j)
                        acc[i][j] = __builtin_amdgcn_mfma_f32_16x16x32_bf16(af[i], bfr[j], acc[i][j], 0, 0, 0);
            }
    }

    const int rb = (lane >> 4) * 4, col = lane & 15;
#pragma unroll
    for (int i = 0; i < 2; ++i)
#pragma unroll
        for (int j = 0; j < 2; ++j)
#pragma unroll
            for (int r = 0; r < 4; ++r) {
                const int gm = m0 + (IA + i) * 16 + rb + r;
                const int gn = n0 + (JB + j) * 16 + col;
                TC* p = &C[(long)gm * ldc + gn];
                if (sizeof(TC) == 2) *(u16*)p = f2bf(acc[i][j][r]);
                else                 *(float*)p = acc[i][j][r];
            }
}

// ---------------- K1: gram 128x128 (256 blk, swizzled) || prep (64 blk) ------
__global__ __launch_bounds__(256) void k_1(const float* __restrict__ x,
                                           const float* __restrict__ qw,
                                           const float* __restrict__ comb,
                                           float* __restrict__ Gp,
                                           u16* __restrict__ qwbf,
                                           u16* __restrict__ combt) {
    __shared__ u16 As[16384];   // 32 KB: 2 x (128m x 64k) fragment blocks
    __shared__ u16 Bs[16384];
    const int bid = blockIdx.x, tid = threadIdx.x;

    if (bid < 256) {            // ---- gram ----
        const int tl = bid & 3, bq = (bid >> 2) & 7, split = bid >> 5;
        const int tm = tl >> 1, tn = tl & 1;
        const int b = bq >> 2, q = bq & 3;
        const int lane = tid & 63, w = tid >> 6;
        const int IA2 = (w & 1), JB2 = (w >> 1);     // wave's 64x64 quadrant

        const float* base = x + (long)b * 2097152 + (long)split * 262144 + q * 256;
        const float* A = base + tm * 128;    // [k=u][m=f], ld 1024
        const float* B = base + tn * 128;
        floatx4 acc[4][4] = {};

#pragma unroll
        for (int burst = 0; burst < 2; ++burst) {
            if (burst) __syncthreads();
#pragma unroll
            for (int kb = 0; kb < 2; ++kb) {
                const long kk = burst * 128 + kb * 64;
                stage_km128_v(A + kk * 1024, 1024, As + kb * 8192, tid);
                stage_km128_v(B + kk * 1024, 1024, Bs + kb * 8192, tid);
            }
            __syncthreads();
#pragma unroll
            for (int kb = 0; kb < 2; ++kb)
#pragma unroll
                for (int s = 0; s < 2; ++s) {
                    short8 af[4], bfr[4];
#pragma unroll
                    for (int i = 0; i < 4; ++i) {
                        const int rA = s * 8 + IA2 * 4 + i;
                        af[i] = *(const short8*)&As[kb * 8192 + (rA * 64 + (lane ^ (rA & 7))) * 8];
                    }
#pragma unroll
                    for (int j = 0; j < 4; ++j) {
                        const int rB = s * 8 + JB2 * 4 + j;
                        bfr[j] = *(const short8*)&Bs[kb * 8192 + (rB * 64 + (lane ^ (rB & 7))) * 8];
                    }
#pragma unroll
                    for (int i = 0; i < 4; ++i)
#pragma unroll
                        for (int j = 0; j < 4; ++j)
                            acc[i][j] = __builtin_amdgcn_mfma_f32_16x16x32_bf16(af[i], bfr[j], acc[i][j], 0, 0, 0);
                }
        }

        float* C = Gp + (long)(split * 8 + bq) * 65536;
        const int rb = (lane >> 4) * 4, col = lane & 15;
#pragma unroll
        for (int i = 0; i < 4; ++i)
#pragma unroll
            for (int j = 0; j < 4; ++j)
#pragma unroll
                for (int r = 0; r < 4; ++r) {
                    const int gm = tm * 128 + IA2 * 64 + i * 16 + rb + r;
                    const int gn = tn * 128 + JB2 * 64 + j * 16 + col;
                    C[(long)gm * 256 + gn] = acc[i][j][r];
                }
    } else {                    // ---- prep: 768 units over 64 blocks ----
        for (int u = bid - 256; u < 768; u += 64) {
            if (u < 512) {                  // qwbf: 512 units x 2048 elems
                const long i = ((long)u * 256 + tid) * 8;
                const float4 a = *(const float4*)&qw[i];
                const float4 b = *(const float4*)&qw[i + 4];
                ushort4 lo, hi;
                lo.x = f2bf(a.x); lo.y = f2bf(a.y); lo.z = f2bf(a.z); lo.w = f2bf(a.w);
                hi.x = f2bf(b.x); hi.y = f2bf(b.y); hi.z = f2bf(b.z); hi.w = f2bf(b.w);
                *(ushort4*)&qwbf[i]     = lo;
                *(ushort4*)&qwbf[i + 4] = hi;
            } else {                        // combt[a][g][qh] = comb[a][qh][g]
                u16 (*T)[66] = (u16(*)[66])As;      // scratch in As
                const int t = u - 512;      // 256 units: 4 a x 16 qh x 4 g
                const int a = t >> 6;
                const int qh0 = ((t >> 2) & 15) * 64, g0 = (t & 3) * 64;
                const float* src = comb + (long)a * 262144;   // [1024 qh][256 g]
                u16* dst = combt + (long)a * 262144;          // [256 g][1024 qh]
                __syncthreads();            // protect T reuse across units
#pragma unroll
                for (int it = 0; it < 4; ++it) {
                    const int flat = (it * 256 + tid) * 4;
                    const int r = flat >> 6, c = flat & 63;
                    const float4 f = *(const float4*)&src[(long)(qh0 + r) * 256 + g0 + c];
                    T[r][c]     = f2bf(f.x); T[r][c + 1] = f2bf(f.y);
                    T[r][c + 2] = f2bf(f.z); T[r][c + 3] = f2bf(f.w);
                }
                __syncthreads();
#pragma unroll
                for (int it = 0; it < 4; ++it) {
                    const int flat = (it * 256 + tid) * 4;
                    const int r = flat >> 6, c = flat & 63;
                    ushort4 v;
                    v.x = T[c][r]; v.y = T[c + 1][r]; v.z = T[c + 2][r]; v.w = T[c + 3][r];
                    *(ushort4*)&dst[(long)(g0 + r) * 1024 + qh0 + c] = v;
                }
            }
        }
    }
}

// gred: Gsbf[bq][f][h] = bf16(sum_{s=0..7} Gp[s][bq][f][h]). 524288 elems.
__global__ __launch_bounds__(256) void k_gred(const float* __restrict__ Gp,
                                              u16* __restrict__ Gs) {
    const long i = ((long)blockIdx.x * 256 + threadIdx.x) * 4;
    float4 acc = *(const float4*)&Gp[i];
#pragma unroll
    for (int s = 1; s < 8; ++s) {
        const float4 f = *(const float4*)&Gp[(long)s * 524288 + i];
        acc.x += f.x; acc.y += f.y; acc.z += f.z; acc.w += f.w;
    }
    ushort4 v;
    v.x = f2bf(acc.x); v.y = f2bf(acc.y); v.z = f2bf(acc.z); v.w = f2bf(acc.w);
    *(ushort4*)&Gs[i] = v;
}

// 2a: Tt[ba][g][q*256+f] = sum_h combt[a][g][q*256+h] * Gsbf[bq][f][h]
__global__ __launch_bounds__(256) void k_2a(const u16* __restrict__ combt,
                                            const u16* __restrict__ Gs,
                                            u16* __restrict__ Tt) {
    const int tile = blockIdx.x, i = blockIdx.y;     // i = ba*4+q
    const int tm = tile >> 2, tn = tile & 3;
    const int q = i & 3, ba = i >> 2, b = ba >> 2, a = ba & 3;
    gemm_tile<0, 0, u16, 1>(
        combt + (long)a * 262144 + (long)tm * 65536 + q * 256, 1024,
        Gs + (long)(b * 4 + q) * 65536 + (long)tn * 16384, 256,
        Tt + (long)ba * 262144, 1024,
        tm * 64, q * 256 + tn * 64);
}

// 2b: Wtbf[ba][g][e] = sum_k Tt[ba][g][k] * qwbf[a][e][k], K=1024 in-block.
__global__ __launch_bounds__(256) void k_2b(const u16* __restrict__ Tt,
                                            const u16* __restrict__ qwbf,
                                            u16* __restrict__ Wt) {
    const int tile = blockIdx.x, ba = blockIdx.y;
    const int tm = tile >> 2, tn = tile & 3;
    const int a = ba & 3;
    gemm_tile<0, 0, u16, 4>(
        Tt + (long)ba * 262144 + (long)tm * 65536, 1024,
        qwbf + (long)a * 262144 + (long)tn * 65536, 1024,
        Wt + (long)ba * 65536, 256,
        tm * 64, tn * 64);
}

// out: out[b][t][a*256+g] = sum_e bf16(x[b][t][a*256+e]) * Wtbf[ba][g][e]
// 64x256 output tile per block (r22/r24 body).
__global__ __launch_bounds__(256) void k_3(const float* __restrict__ x,
                                           const u16* __restrict__ Wt,
                                           float* __restrict__ out) {
    __shared__ u16 As[4096];    //  8 KB: 64t x 64e fragment block
    __shared__ u16 Bs[16384];   // 32 KB: 4 g-blocks x (64g x 64e)
    const int tm = blockIdx.x, ba = blockIdx.y;      // tm 0..31, ba 0..7
    const int b = ba >> 2, a = ba & 3;
    const int tid = threadIdx.x, lane = tid & 63, w = tid >> 6;
    const float* A = x + (long)b * 2097152 + (long)tm * 65536 + a * 256;  // ld 1024
    const u16*   B = Wt + (long)ba * 65536;                               // [256 g][256 e]
    floatx4 acc[4][4] = {};

#pragma unroll
    for (int kb = 0; kb < 4; ++kb) {
        if (kb) __syncthreads();
        stage64_f32(A + kb * 64, 1024, As, tid);
#pragma unroll
        for (int jb = 0; jb < 4; ++jb)
            stage64_bf(B + (long)jb * 16384 + kb * 64, 256, Bs + jb * 4096, tid);
        __syncthreads();
#pragma unroll
        for (int s = 0; s < 2; ++s) {
            short8 af[4], bfr[4];
#pragma unroll
            for (int i = 0; i < 4; ++i)
                af[i] = *(const short8*)&As[((s * 4 + i) * 64 + lane) * 8];
#pragma unroll
            for (int j = 0; j < 4; ++j)
                bfr[j] = *(const short8*)&Bs[w * 4096 + ((s * 4 + j) * 64 + lane) * 8];
#pragma unroll
            for (int i = 0; i < 4; ++i)
#pragma unroll
                for (int j = 0; j < 4; ++j)
                    acc[i][j] = __builtin_amdgcn_mfma_f32_16x16x32_bf16(af[i], bfr[j], acc[i][j], 0, 0, 0);
        }
    }

    float* C = out + (long)b * 2097152 + a * 256;
    const int rb = (lane >> 4) * 4, col = lane & 15;
#pragma unroll
    for (int i = 0; i < 4; ++i)
#pragma unroll
        for (int j = 0; j < 4; ++j)
#pragma unroll
            for (int r = 0; r < 4; ++r) {
                const int gm = tm * 64 + i * 16 + rb + r;          // t row
                const int gn = w * 64 + j * 16 + col;              // g col (0..255)
                C[(long)gm * 1024 + gn] = acc[i][j][r];
            }
}

extern "C" void kernel_launch(void* const* d_in, const int* in_sizes, int n_in,
                              void* d_out, int out_size, void* d_ws, size_t ws_size,
                              hipStream_t stream) {
    const float* x    = (const float*)d_in[0];   // [2,2048,1024]
    const float* qw   = (const float*)d_in[1];   // [4,256,1024]
    const float* comb = (const float*)d_in[2];   // [4,1024,256]
    float* out = (float*)d_out;

    char* ws = (char*)d_ws;
    float* Gp   = (float*)(ws);                  // 16 MB [8 split][8 bq][256x256]
    u16*   Tt   = (u16*)  (ws + (16u << 20));    //  4 MB [8][256][1024] bf16
    u16*   qwbf = (u16*)  (ws + (20u << 20));    //  2 MB [4][256][1024] bf16
    u16*   combt= (u16*)  (ws + (22u << 20));    //  2 MB [4][256][1024] bf16 (comb^T)
    u16*   Wtbf = (u16*)  (ws + (24u << 20));    //  1 MB [8][256][256] bf16
    u16*   Gsbf = (u16*)  (ws + (25u << 20));    //  1 MB [8 bq][256][256] bf16

    k_1   <<<dim3(320),    256, 0, stream>>>(x, qw, comb, Gp, qwbf, combt);
    k_gred<<<dim3(512),    256, 0, stream>>>(Gp, Gsbf);
    k_2a  <<<dim3(16, 32), 256, 0, stream>>>(combt, Gsbf, Tt);
    k_2b  <<<dim3(16, 8),  256, 0, stream>>>(Tt, qwbf, Wtbf);
    k_3   <<<dim3(32, 8),  256, 0, stream>>>(x, Wtbf, out);
}